// Round 5
// baseline (99.819 us; speedup 1.0000x reference)
//
#include <hip/hip_runtime.h>

// Problem constants (match reference)
#define S_AR 3072
#define NH 16
#define NB 4
#define ND 128
#define NTOT (S_AR * NH * NB * ND)   // 25,165,824 elems per tensor
#define N8   (NTOT / 8)              // 3,145,728 float8 per tensor
#define TPB 256
#define HALF_BLOCKS 2048             // blocks per tensor
#define STRIDE (HALF_BLOCKS * TPB)   // 524,288 threads per tensor
#define ITERS (N8 / STRIDE)          // exactly 6, no remainder

// Native clang vector types — required by __builtin_nontemporal_{load,store}
typedef float vf8 __attribute__((ext_vector_type(8)));

__device__ __forceinline__ float max8abs(vf8 a) {
    float m0 = fmaxf(fmaxf(fabsf(a.s0), fabsf(a.s1)), fmaxf(fabsf(a.s2), fabsf(a.s3)));
    float m1 = fmaxf(fmaxf(fabsf(a.s4), fabsf(a.s5)), fmaxf(fabsf(a.s6), fabsf(a.s7)));
    return fmaxf(m0, m1);
}

// K/V-split streaming dequant at 32 B/thread granularity.
// Blocks [0,HALF_BLOCKS) stream the K cache, the rest the V cache.
// One (s,h,b) row = 128 floats = 16 float8 = one 16-lane group, so the
// abs-max over D for the special row reduces via __shfl_xor offsets 8,4,2,1.
__global__ void __launch_bounds__(TPB) kv_dequant_split8(
    const vf8* __restrict__ key8, const vf8* __restrict__ val8,
    const vf8* __restrict__ ck,   const vf8* __restrict__ cv,
    const float* __restrict__ ksc, const float* __restrict__ vsc,
    const int* __restrict__ idxp,
    vf8* __restrict__ ok, vf8* __restrict__ ov)
{
    const float inv = 1.0f / 127.5f;
    const int idx  = *idxp;                       // uniform scalar load
    const int half = blockIdx.x >> 11;            // 0 = K, 1 = V
    const int tid  = (blockIdx.x & (HALF_BLOCKS - 1)) * TPB + threadIdx.x;

    const vf8*   src  = half ? cv   : ck;
    const float* sc   = half ? vsc  : ksc;
    const vf8*   new8 = half ? val8 : key8;
    vf8*         dst  = half ? ov   : ok;

    #pragma unroll
    for (int it = 0; it < ITERS; ++it) {
        const int i   = tid + it * STRIDE;
        const int row = i >> 4;                   // (s,h,b) flat row
        vf8 x = __builtin_nontemporal_load(&src[i]);
        x *= sc[row] * inv;
        if (__builtin_expect((row >> 6) == idx, 0)) {   // s == idx : new step
            const int h = (row >> 2) & 15;
            const int b = row & 3;
            const vf8 n = new8[(b * NH + h) * (ND / 8) + (i & 15)];
            float m = max8abs(n);
            #pragma unroll
            for (int o = 8; o; o >>= 1)           // stays within 16-lane group
                m = fmaxf(m, __shfl_xor(m, o));
            const float q = 127.5f / m, d = m * inv;
            x.s0 = rintf(n.s0 * q) * d; x.s1 = rintf(n.s1 * q) * d;
            x.s2 = rintf(n.s2 * q) * d; x.s3 = rintf(n.s3 * q) * d;
            x.s4 = rintf(n.s4 * q) * d; x.s5 = rintf(n.s5 * q) * d;
            x.s6 = rintf(n.s6 * q) * d; x.s7 = rintf(n.s7 * q) * d;
        }
        __builtin_nontemporal_store(x, &dst[i]);
    }
}

extern "C" void kernel_launch(void* const* d_in, const int* in_sizes, int n_in,
                              void* d_out, int out_size, void* d_ws, size_t ws_size,
                              hipStream_t stream) {
    const float* key   = (const float*)d_in[0];
    const float* value = (const float*)d_in[1];
    const float* ck    = (const float*)d_in[2];
    const float* cv    = (const float*)d_in[3];
    const float* ksc   = (const float*)d_in[4];
    const float* vsc   = (const float*)d_in[5];
    const int*   idxp  = (const int*)d_in[6];

    float* out_k = (float*)d_out;
    float* out_v = (float*)d_out + NTOT;

    kv_dequant_split8<<<dim3(2 * HALF_BLOCKS), dim3(TPB), 0, stream>>>(
        (const vf8*)key, (const vf8*)value,
        (const vf8*)ck, (const vf8*)cv,
        ksc, vsc, idxp,
        (vf8*)out_k, (vf8*)out_v);
}

// Round 6
// 75.364 us; speedup vs baseline: 1.3245x; 1.3245x over previous
//
#include <hip/hip_runtime.h>

// Problem constants (match reference)
#define S_AR 3072
#define NH 16
#define NB 4
#define ND 128
#define NTOT (S_AR * NH * NB * ND)   // 25,165,824 elems per tensor
#define N4   (NTOT / 4)              // 6,291,456 float4 per tensor
#define TPB 256
#define HALF_BLOCKS 2048             // blocks per tensor
#define STRIDE (HALF_BLOCKS * TPB)   // 524,288 threads per tensor
#define ITERS (N4 / STRIDE)          // exactly 12, no remainder

// Native clang vector type — required by __builtin_nontemporal_{load,store}
typedef float vf4 __attribute__((ext_vector_type(4)));

__device__ __forceinline__ float max4abs(vf4 a) {
    return fmaxf(fmaxf(fabsf(a.x), fabsf(a.y)), fmaxf(fabsf(a.z), fabsf(a.w)));
}

// K/V-split streaming dequant, 16 B/lane contiguous (per-instruction coalesced).
// Blocks [0,HALF_BLOCKS) stream the K cache, the rest the V cache.
// Scales for all 12 iterations are prefetched up front so the streaming loop
// is pure NT-load -> mul -> NT-store. One (s,h,b) row = 32 float4 = one
// aligned 32-lane group; special row s==idx reduces abs-max via __shfl_xor.
__global__ void __launch_bounds__(TPB) kv_dequant_split(
    const vf4* __restrict__ key4, const vf4* __restrict__ val4,
    const vf4* __restrict__ ck,   const vf4* __restrict__ cv,
    const float* __restrict__ ksc, const float* __restrict__ vsc,
    const int* __restrict__ idxp,
    vf4* __restrict__ ok, vf4* __restrict__ ov)
{
    const float inv = 1.0f / 127.5f;
    const int idx  = *idxp;                       // uniform scalar load
    const int half = blockIdx.x >> 11;            // 0 = K, 1 = V
    const int tid  = (blockIdx.x & (HALF_BLOCKS - 1)) * TPB + threadIdx.x;

    const vf4*   src  = half ? cv   : ck;
    const float* sc   = half ? vsc  : ksc;
    const vf4*   new4 = half ? val4 : key4;
    vf4*         dst  = half ? ov   : ok;

    // Prefetch per-iteration scales (one dword per 32-lane group, L1-broadcast)
    float s[ITERS];
    #pragma unroll
    for (int it = 0; it < ITERS; ++it)
        s[it] = sc[(tid + it * STRIDE) >> 5] * inv;

    #pragma unroll
    for (int it = 0; it < ITERS; ++it) {
        const int i = tid + it * STRIDE;
        vf4 x = __builtin_nontemporal_load(&src[i]);
        x *= s[it];
        if (__builtin_expect((i >> 11) == idx, 0)) {    // s == idx : new step
            const int row = i >> 5;
            const int h = (row >> 2) & 15;
            const int b = row & 3;
            const vf4 n = new4[(b * NH + h) * (ND / 4) + (i & 31)];
            float m = max4abs(n);
            #pragma unroll
            for (int o = 16; o; o >>= 1)          // stays within 32-lane group
                m = fmaxf(m, __shfl_xor(m, o));
            const float q = 127.5f / m, d = m * inv;
            x.x = rintf(n.x * q) * d; x.y = rintf(n.y * q) * d;
            x.z = rintf(n.z * q) * d; x.w = rintf(n.w * q) * d;
        }
        __builtin_nontemporal_store(x, &dst[i]);
    }
}

extern "C" void kernel_launch(void* const* d_in, const int* in_sizes, int n_in,
                              void* d_out, int out_size, void* d_ws, size_t ws_size,
                              hipStream_t stream) {
    const float* key   = (const float*)d_in[0];
    const float* value = (const float*)d_in[1];
    const float* ck    = (const float*)d_in[2];
    const float* cv    = (const float*)d_in[3];
    const float* ksc   = (const float*)d_in[4];
    const float* vsc   = (const float*)d_in[5];
    const int*   idxp  = (const int*)d_in[6];

    float* out_k = (float*)d_out;
    float* out_v = (float*)d_out + NTOT;

    kv_dequant_split<<<dim3(2 * HALF_BLOCKS), dim3(TPB), 0, stream>>>(
        (const vf4*)key, (const vf4*)value,
        (const vf4*)ck, (const vf4*)cv,
        ksc, vsc, idxp,
        (vf4*)out_k, (vf4*)out_v);
}